// Round 9
// baseline (104.776 us; speedup 1.0000x reference)
//
#include <hip/hip_runtime.h>
#include <math.h>

#define NT 13
#define RHW 57600  // 240*240

typedef unsigned long long ull;

struct Meta {
  const float* x[NT];
  int C[NT];
  int H[NT];
  float hsc[NT];            // (float)((double)H/240.0), host-computed
  int chanOff[NT + 1];      // global channel index offsets
  int pixOff[NT + 1];       // per-tensor pixel offsets
  int nibOff[NT];           // u16 offsets into nibble cache (C*HW/4 per tensor)
  int pmOff[NT + 1];        // pmap block offsets (256 px per block)
};

__device__ __forceinline__ int segOf(const int* off, int b) {
  int t = 0;
  while (t + 1 < NT && b >= off[t + 1]) t++;
  return t;
}

// ---------------- pass A helpers: guarded min/max of one float4 ----------------
template <int HH>
__device__ __forceinline__ void mmProc(int i4, bool g, float4 v, float& mn, float& mx) {
  constexpr int W = HH, H = HH;
  if (!g) return;
#pragma unroll
  for (int j = 0; j < 4; j++) {
    int idx = i4 * 4 + j;
    int h = idx / W, w = idx - h * W;   // compile-time magic div
    bool ok = h > 0 && h < (H - 1) && w > 0 && w < (W - 1);
    float f = (j == 0) ? v.x : (j == 1) ? v.y : (j == 2) ? v.z : v.w;
    if (ok) { mn = fminf(mn, f); mx = fmaxf(mx, f); }
  }
}

// ---------------- pass B helpers: guarded hist + nibble of one float4 ----------------
template <int HH>
__device__ __forceinline__ void histProc(int i4, bool g, float4 v, float mn, float invd,
                                         ull& cbin, ull& clut, unsigned short* __restrict__ nb) {
  constexpr int W = HH, H = HH;
  if (!g) return;
  unsigned pack = 0;
#pragma unroll
  for (int j = 0; j < 4; j++) {
    int idx = i4 * 4 + j;
    int h = idx / W, w = idx - h * W;
    bool intr = h > 0 && h < (H - 1) && w > 0 && w < (W - 1);
    float f = (j == 0) ? v.x : (j == 1) ? v.y : (j == 2) ? v.z : v.w;
    float vv = (f - mn) * invd * 256.0f;
    int bin = (int)(vv * 0.0234375f);  // * (6/256)
    bin = bin < 0 ? 0 : (bin > 5 ? 5 : bin);
    float tt = vv * 6.0f - 1.0f;
    int li = (int)tt;                  // trunc toward zero, matches astype(int32)
    li = li < 0 ? 0 : (li > 5 ? 5 : li);
    cbin += (ull)intr << (bin * 10);
    clut += (ull)intr << (li * 10);
    pack |= (unsigned)(intr ? li : 7) << (4 * j);  // border -> LUT slot 7
  }
  nb[i4] = (unsigned short)pack;
}

// ---------------- 4-deep pipelined pass bodies (1024 threads) ----------------
template <int HH>
__device__ __forceinline__ void mmA(const float* __restrict__ ch, float& mn, float& mx) {
  constexpr int f4n = (HH * HH) / 4;
  const float4* __restrict__ P = reinterpret_cast<const float4*>(ch);
  const float4 z = make_float4(0.f, 0.f, 0.f, 0.f);
  for (int base = (int)threadIdx.x; base < f4n; base += 4096) {
    int i1 = base + 1024, i2 = base + 2048, i3 = base + 3072;
    bool g1 = i1 < f4n, g2 = i2 < f4n, g3 = i3 < f4n;
    float4 v0 = P[base];
    float4 v1 = g1 ? P[i1] : z;
    float4 v2 = g2 ? P[i2] : z;
    float4 v3 = g3 ? P[i3] : z;
    mmProc<HH>(base, true, v0, mn, mx);
    mmProc<HH>(i1, g1, v1, mn, mx);
    mmProc<HH>(i2, g2, v2, mn, mx);
    mmProc<HH>(i3, g3, v3, mn, mx);
  }
}

template <int HH>
__device__ __forceinline__ void histB(const float* __restrict__ ch, unsigned short* __restrict__ nb,
                                      float mn, float invd, ull& cbin, ull& clut) {
  constexpr int f4n = (HH * HH) / 4;
  const float4* __restrict__ P = reinterpret_cast<const float4*>(ch);
  const float4 z = make_float4(0.f, 0.f, 0.f, 0.f);
  for (int base = (int)threadIdx.x; base < f4n; base += 4096) {
    int i1 = base + 1024, i2 = base + 2048, i3 = base + 3072;
    bool g1 = i1 < f4n, g2 = i2 < f4n, g3 = i3 < f4n;
    float4 v0 = P[base];
    float4 v1 = g1 ? P[i1] : z;
    float4 v2 = g2 ? P[i2] : z;
    float4 v3 = g3 ? P[i3] : z;
    histProc<HH>(base, true, v0, mn, invd, cbin, clut, nb);
    histProc<HH>(i1, g1, v1, mn, invd, cbin, clut, nb);
    histProc<HH>(i2, g2, v2, mn, invd, cbin, clut, nb);
    histProc<HH>(i3, g3, v3, mn, invd, cbin, clut, nb);
  }
}

// ---------------- per-channel LUT math (hh = full-mask dual histograms) ----------------
__device__ __forceinline__ void lutMath(int c, int H, int HW, float mn, float invd,
                                        unsigned* hh, float* LUT /*[7]*/) {
  float fHW = (float)HW;
  int nbp = 4 * H - 4;  // border pixel count (W==H)
  float vb = (0.f - mn) * invd * 256.0f;
  int bin_b = (int)(vb * 0.0234375f);
  bin_b = bin_b < 0 ? 0 : (bin_b > 5 ? 5 : bin_b);
  float ttb = vb * 6.0f - 1.0f;
  int lib = (int)ttb;
  lib = lib < 0 ? 0 : (lib > 5 ? 5 : lib);
  hh[bin_b] += (unsigned)nbp;   // reconstruct full-mask histograms (border value 0)
  hh[6 + lib] += (unsigned)nbp;
  float hl[6];
#pragma unroll
  for (int j = 0; j < 6; j++) hl[j] = -logf((float)hh[j] / fHW + 1e-4f);
  float mn2 = INFINITY, mx2 = -INFINITY, sum2 = 0.f;
#pragma unroll
  for (int j = 0; j < 6; j++) {
    unsigned cc = hh[6 + j];
    if (cc) { mn2 = fminf(mn2, hl[j]); mx2 = fmaxf(mx2, hl[j]); sum2 += (float)cc * hl[j]; }
  }
  float d2 = mx2 - mn2;
  float RL[6];
  if (d2 > 0.f) {
    float meanN = (sum2 / fHW - mn2) / d2;
    float w = 1.0f - meanN; w *= w;
#pragma unroll
    for (int j = 0; j < 6; j++) RL[j] = (hl[j] - mn2) / d2 * w;
  } else {
#pragma unroll
    for (int j = 0; j < 6; j++) RL[j] = 0.f;
  }
  if (c == 0) {
    float mnr = INFINITY, mxr = -INFINITY, sumr = 0.f;
#pragma unroll
    for (int j = 0; j < 6; j++) {
      unsigned cc = hh[6 + j];
      if (cc) { mnr = fminf(mnr, RL[j]); mxr = fmaxf(mxr, RL[j]); sumr += (float)cc * RL[j]; }
    }
    float dr = mxr - mnr;
    if (dr > 0.f) {
      float meanr = sumr / fHW;
      float wp = mxr - meanr; wp *= wp;
#pragma unroll
      for (int j = 0; j < 6; j++) LUT[j] = (RL[j] - mnr) / dr * wp;
      LUT[6] = LUT[lib];
    } else {
#pragma unroll
      for (int j = 0; j < 7; j++) LUT[j] = 0.f;
    }
  } else {
    float mnr = 0.f, mxr = 0.f, sumr = 0.f;
#pragma unroll
    for (int j = 0; j < 6; j++) {
      int cc = (int)hh[6 + j] - (j == lib ? nbp : 0);
      if (cc > 0) { mnr = fminf(mnr, RL[j]); mxr = fmaxf(mxr, RL[j]); sumr += (float)cc * RL[j]; }
    }
    float dr = mxr - mnr;
    if (dr > 0.f) {
      float meanr = sumr / fHW;
      float wp = mxr - meanr; wp *= wp;
#pragma unroll
      for (int j = 0; j < 6; j++) LUT[j] = (RL[j] - mnr) / dr * wp;
      LUT[6] = (0.f - mnr) / dr * wp;
    } else {
#pragma unroll
      for (int j = 0; j < 7; j++) LUT[j] = 0.f;
    }
  }
}

// ---------------- K1: one 1024-thread block per channel: minmax + hist + nibble + LUT ----------------
__global__ __launch_bounds__(1024) void k_chan(Meta m, unsigned short* __restrict__ nib,
                                               float* __restrict__ lutg) {
  int b = blockIdx.x;
  int t = segOf(m.chanOff, b);
  int c = b - m.chanOff[t];
  int H = m.H[t], HW = H * H;
  const float* ch = m.x[t] + (size_t)c * HW;
  int tid = threadIdx.x, wid = tid >> 6, lane = tid & 63;

  // pass A: interior min/max (4-deep pipelined)
  float mn = INFINITY, mx = -INFINITY;
  switch (H) {
    case 224: mmA<224>(ch, mn, mx); break;
    case 112: mmA<112>(ch, mn, mx); break;
    case 56:  mmA<56>(ch, mn, mx); break;
    case 28:  mmA<28>(ch, mn, mx); break;
    default:  mmA<14>(ch, mn, mx); break;
  }
#pragma unroll
  for (int o = 32; o > 0; o >>= 1) {
    mn = fminf(mn, __shfl_down(mn, o));
    mx = fmaxf(mx, __shfl_down(mx, o));
  }
  __shared__ float smn[16], smx[16];
  __shared__ float sMn, sInv;
  if (lane == 0) { smn[wid] = mn; smx[wid] = mx; }
  __syncthreads();
  if (tid == 0) {
    for (int i = 1; i < 16; i++) { mn = fminf(mn, smn[i]); mx = fmaxf(mx, smx[i]); }
    mn = fminf(mn, 0.f); mx = fmaxf(mx, 0.f);   // fold border zeros
    float d = mx - mn;
    sMn = mn; sInv = d > 0.f ? 1.0f / d : 0.f;
  }
  __syncthreads();
  float mnc = sMn, invd = sInv;

  // pass B: histograms + nibble cache (L2-hot re-read, 4-deep pipelined)
  unsigned short* nb = nib + m.nibOff[t] + (size_t)c * (HW >> 2);
  ull cbin = 0ull, clut = 0ull;
  switch (H) {
    case 224: histB<224>(ch, nb, mnc, invd, cbin, clut); break;
    case 112: histB<112>(ch, nb, mnc, invd, cbin, clut); break;
    case 56:  histB<56>(ch, nb, mnc, invd, cbin, clut); break;
    case 28:  histB<28>(ch, nb, mnc, invd, cbin, clut); break;
    default:  histB<14>(ch, nb, mnc, invd, cbin, clut); break;
  }
  // per-lane counts <= 52 per field; pack lo|hi 16-bit (sums < 65536) and reduce
  unsigned pk[6];
#pragma unroll
  for (int j = 0; j < 6; j++)
    pk[j] = (unsigned)((cbin >> (10 * j)) & 1023ull) |
            ((unsigned)((clut >> (10 * j)) & 1023ull) << 16);
#pragma unroll
  for (int o = 32; o > 0; o >>= 1) {
#pragma unroll
    for (int j = 0; j < 6; j++) pk[j] += __shfl_down(pk[j], o);
  }
  __shared__ unsigned spk[16][6];
  if (lane == 0) {
#pragma unroll
    for (int j = 0; j < 6; j++) spk[wid][j] = pk[j];
  }
  __syncthreads();
  if (tid == 0) {
    unsigned hh[12];
#pragma unroll
    for (int j = 0; j < 6; j++) {
      unsigned s = 0;
#pragma unroll
      for (int w = 0; w < 16; w++) s += spk[w][j];
      hh[j] = s & 0xffffu; hh[6 + j] = s >> 16;
    }
    float LUT[7];
    lutMath(c, H, HW, mnc, invd, hh, LUT);
    float* o = lutg + (size_t)b * 8;
#pragma unroll
    for (int j = 0; j < 6; j++) o[j] = LUT[j];
    o[6] = LUT[6]; o[7] = LUT[6];   // slot 7 = border
  }
}

// ---------------- K2: p map from nibble cache (LUTs in LDS) ----------------
__global__ __launch_bounds__(256) void k_pmap(Meta m, const unsigned short* __restrict__ nib,
                                              const float* __restrict__ lutg,
                                              float* __restrict__ pmaps, float* __restrict__ ppart) {
  __shared__ float sLut[512 * 8];   // 16 KB
  __shared__ float sAcc[4][256];
  int b = blockIdx.x;
  int t = segOf(m.pmOff, b);
  int blk = b - m.pmOff[t];
  int C = m.C[t], HW = m.H[t] * m.H[t], i4n = HW >> 2;
  int tid = threadIdx.x, wid = tid >> 6, lane = tid & 63;
  const float4* Lg = reinterpret_cast<const float4*>(lutg + (size_t)m.chanOff[t] * 8);
  for (int i = tid; i < C * 2; i += 256) reinterpret_cast<float4*>(sLut)[i] = Lg[i];
  __syncthreads();
  int i4 = blk * 64 + lane;
  bool act = i4 < i4n;
  float a0 = 0.f, a1 = 0.f, a2 = 0.f, a3 = 0.f;
  if (act) {
    const unsigned short* nb = nib + m.nibOff[t] + i4;
    int cpw = C >> 2;
    int c0 = wid * cpw, c1 = c0 + cpw;
#pragma unroll 4
    for (int c = c0; c < c1; ++c) {
      unsigned n = nb[(size_t)c * i4n];
      a0 += sLut[c * 8 + (int)(n & 7u)];
      a1 += sLut[c * 8 + (int)((n >> 4) & 7u)];
      a2 += sLut[c * 8 + (int)((n >> 8) & 7u)];
      a3 += sLut[c * 8 + (int)((n >> 12) & 7u)];
    }
  }
  *reinterpret_cast<float4*>(&sAcc[wid][lane * 4]) = make_float4(a0, a1, a2, a3);
  __syncthreads();
  if (wid == 0) {
    float bmn = INFINITY, bmx = -INFINITY;
    if (act) {
      float t0 = 0.f, t1 = 0.f, t2 = 0.f, t3 = 0.f;
#pragma unroll
      for (int w = 0; w < 4; w++) {   // ascending w == ascending channel blocks (ref order)
        const float* s = &sAcc[w][lane * 4];
        t0 += s[0]; t1 += s[1]; t2 += s[2]; t3 += s[3];
      }
      *reinterpret_cast<float4*>(pmaps + (size_t)m.pixOff[t] + (size_t)i4 * 4) =
          make_float4(t0, t1, t2, t3);
      bmn = fminf(fminf(t0, t1), fminf(t2, t3));
      bmx = fmaxf(fmaxf(t0, t1), fmaxf(t2, t3));
    }
#pragma unroll
    for (int o = 32; o > 0; o >>= 1) {
      bmn = fminf(bmn, __shfl_down(bmn, o));
      bmx = fmaxf(bmx, __shfl_down(bmx, o));
    }
    if (lane == 0) { ppart[2 * b] = bmn; ppart[2 * b + 1] = bmx; }
  }
}

// ---------------- K3: bilinear resize + norm; per-block (mn,mx,sum) partials ----------------
__global__ __launch_bounds__(256) void k_resize(Meta m, const float* pmaps, const float* ppart,
                                                float* mmaps, float* rpart) {
  __shared__ float sMnT, sInvT;
  int t = blockIdx.x / 225;
  int blk = blockIdx.x % 225;
  int wid = threadIdx.x >> 6, lane = threadIdx.x & 63;
  if (wid == 0) {
    int n = m.pmOff[t + 1] - m.pmOff[t];        // <= 196 partials
    const float* pp = ppart + (size_t)m.pmOff[t] * 2;
    float mn = INFINITY, mx = -INFINITY;
    for (int i = lane; i < n; i += 64) { mn = fminf(mn, pp[2 * i]); mx = fmaxf(mx, pp[2 * i + 1]); }
#pragma unroll
    for (int o = 32; o > 0; o >>= 1) {
      mn = fminf(mn, __shfl_down(mn, o));
      mx = fmaxf(mx, __shfl_down(mx, o));
    }
    if (lane == 0) {
      float d = mx - mn;
      sMnT = mn; sInvT = d > 0.f ? 1.0f / d : 0.f;
    }
  }
  __syncthreads();
  int pix = blk * 256 + threadIdx.x;  // 225*256 == 57600 exactly
  int H = m.H[t], W = m.H[t];
  const float* p = pmaps + m.pixOff[t];
  float mn = sMnT, a = sInvT;
  int oy = pix / 240, ox = pix - oy * 240;
  float hs = m.hsc[t];
  float sy = ((float)oy + 0.5f) * hs - 0.5f;
  float sx = ((float)ox + 0.5f) * hs - 0.5f;
  float fy0 = floorf(sy), fx0 = floorf(sx);
  float fy = sy - fy0, fx = sx - fx0;
  int iy0 = (int)fy0, ix0 = (int)fx0;
  int y0 = iy0 < 0 ? 0 : (iy0 > H - 1 ? H - 1 : iy0);
  int y1 = iy0 + 1 < 0 ? 0 : (iy0 + 1 > H - 1 ? H - 1 : iy0 + 1);
  int x0 = ix0 < 0 ? 0 : (ix0 > W - 1 ? W - 1 : ix0);
  int x1 = ix0 + 1 < 0 ? 0 : (ix0 + 1 > W - 1 ? W - 1 : ix0 + 1);
  float v00 = p[y0 * W + x0], v01 = p[y0 * W + x1];
  float v10 = p[y1 * W + x0], v11 = p[y1 * W + x1];
  float r = (1.f - fy) * ((1.f - fx) * v00 + fx * v01) + fy * ((1.f - fx) * v10 + fx * v11);
  float mv = (r - mn) * a;
  mmaps[(size_t)t * RHW + pix] = mv;
  float bmn = mv, bmx = mv, bsm = mv;
#pragma unroll
  for (int o = 32; o > 0; o >>= 1) {
    bmn = fminf(bmn, __shfl_down(bmn, o));
    bmx = fmaxf(bmx, __shfl_down(bmx, o));
    bsm += __shfl_down(bsm, o);
  }
  __shared__ float smn[4], smx[4], ssm[4];
  if ((threadIdx.x & 63) == 0) { smn[wid] = bmn; smx[wid] = bmx; ssm[wid] = bsm; }
  __syncthreads();
  if (threadIdx.x == 0) {
    for (int i = 1; i < 4; i++) { bmn = fminf(bmn, smn[i]); bmx = fmaxf(bmx, smx[i]); bsm += ssm[i]; }
    float* rp = rpart + ((size_t)t * 225 + blk) * 3;
    rp[0] = bmn; rp[1] = bmx; rp[2] = bsm;
  }
}

// ---------------- K4: fuse group (inline partial reduce) ----------------
__global__ __launch_bounds__(256) void k_fuse(const float* mmaps, const float* rpart,
                                              float* fusedm, float* fpart) {
  __shared__ float sMn[3], sD[3], sW[3];
  int g = blockIdx.x / 225;
  int blk = blockIdx.x % 225;
  const int gs[6] = {0, 2, 4, 7, 10, 13};
  int nt = gs[g + 1] - gs[g];
  int wid = threadIdx.x >> 6, lane = threadIdx.x & 63;
  if (wid < nt) {
    int t = gs[g] + wid;
    const float* rp = rpart + (size_t)t * 225 * 3;
    float mn = INFINITY, mx = -INFINITY, sm = 0.f;
    for (int i = lane; i < 225; i += 64) {
      mn = fminf(mn, rp[3 * i]); mx = fmaxf(mx, rp[3 * i + 1]); sm += rp[3 * i + 2];
    }
#pragma unroll
    for (int o = 32; o > 0; o >>= 1) {
      mn = fminf(mn, __shfl_down(mn, o));
      mx = fmaxf(mx, __shfl_down(mx, o));
      sm += __shfl_down(sm, o);
    }
    if (lane == 0) {
      float d = mx - mn;
      if (d > 0.f) {
        float mean = sm * (1.0f / 57600.0f);
        float w = mx - mean; w *= w;
        sMn[wid] = mn; sD[wid] = d; sW[wid] = w;
      } else {
        sMn[wid] = 0.f; sD[wid] = 0.f; sW[wid] = 0.f;
      }
    }
  }
  __syncthreads();
  int pix = blk * 256 + threadIdx.x;
  float acc = 0.f;
  for (int k = 0; k < nt; k++) {
    int t = gs[g] + k;
    if (sD[k] > 0.f) acc += (mmaps[(size_t)t * RHW + pix] - sMn[k]) / sD[k] * sW[k];
  }
  fusedm[(size_t)g * RHW + pix] = acc;
  float bmn = acc, bmx = acc;
#pragma unroll
  for (int o = 32; o > 0; o >>= 1) {
    bmn = fminf(bmn, __shfl_down(bmn, o));
    bmx = fmaxf(bmx, __shfl_down(bmx, o));
  }
  __shared__ float smn[4], smx[4];
  if ((threadIdx.x & 63) == 0) { smn[wid] = bmn; smx[wid] = bmx; }
  __syncthreads();
  if (threadIdx.x == 0) {
    for (int i = 1; i < 4; i++) { bmn = fminf(bmn, smn[i]); bmx = fmaxf(bmx, smx[i]); }
    float* fp = fpart + ((size_t)g * 225 + blk) * 2;
    fp[0] = bmn; fp[1] = bmx;
  }
}

// ---------------- K5: final outputs (inline fstats reduce) ----------------
__global__ __launch_bounds__(256) void k_out(const float* fusedm, const float* fpart, float* out) {
  __shared__ float fmn[5], finv[5];
  int wid = threadIdx.x >> 6, lane = threadIdx.x & 63;
  for (int g = wid; g < 5; g += 4) {
    const float* fp = fpart + (size_t)g * 225 * 2;
    float mn = INFINITY, mx = -INFINITY;
    for (int i = lane; i < 225; i += 64) {
      mn = fminf(mn, fp[2 * i]); mx = fmaxf(mx, fp[2 * i + 1]);
    }
#pragma unroll
    for (int o = 32; o > 0; o >>= 1) {
      mn = fminf(mn, __shfl_down(mn, o));
      mx = fmaxf(mx, __shfl_down(mx, o));
    }
    if (lane == 0) {
      float d = mx - mn;
      fmn[g] = mn; finv[g] = d > 0.f ? 256.0f / d : 0.f;
    }
  }
  __syncthreads();
  int pix = blockIdx.x * 256 + threadIdx.x;
  float acc = 0.f;
  float* out2 = out + RHW;
#pragma unroll
  for (int g = 0; g < 5; g++) {
    float v = (fusedm[(size_t)g * RHW + pix] - fmn[g]) * finv[g];
    out2[(size_t)pix * 5 + g] = v;
    acc += v;
  }
  out[pix] = acc;
}

extern "C" void kernel_launch(void* const* d_in, const int* in_sizes, int n_in,
                              void* d_out, int out_size, void* d_ws, size_t ws_size,
                              hipStream_t stream) {
  static const int Cs[NT] = {64, 64, 128, 128, 256, 256, 256, 512, 512, 512, 512, 512, 512};
  static const int Hs[NT] = {224, 224, 112, 112, 56, 56, 56, 28, 28, 28, 14, 14, 14};
  Meta m;
  int co = 0, po = 0, pmb = 0, nibTot = 0;
  for (int t = 0; t < NT; t++) {
    m.x[t] = (const float*)d_in[t];
    m.C[t] = Cs[t]; m.H[t] = Hs[t];
    m.hsc[t] = (float)((double)Hs[t] / 240.0);
    int HW = Hs[t] * Hs[t];
    m.chanOff[t] = co; co += Cs[t];
    m.pixOff[t] = po; po += HW;
    m.nibOff[t] = nibTot; nibTot += Cs[t] * (HW >> 2);
    m.pmOff[t] = pmb; pmb += (HW + 255) / 256;
  }
  m.chanOff[NT] = co; m.pixOff[NT] = po; m.pmOff[NT] = pmb;

  size_t off = 0;
  auto a16 = [](size_t x) { return (x + 15) & ~(size_t)15; };
#define WALLOC(var, type, count) type* var = (type*)((char*)d_ws + off); off = a16(off + sizeof(type) * (size_t)(count));
  WALLOC(nib, unsigned short, nibTot)
  WALLOC(lutg, float, 8 * co)
  WALLOC(ppart, float, 2 * pmb)
  WALLOC(rpart, float, NT * 225 * 3)
  WALLOC(fpart, float, 5 * 225 * 2)
  WALLOC(pmaps, float, po)
  WALLOC(mmaps, float, NT * RHW)
  WALLOC(fusedm, float, 5 * RHW)
#undef WALLOC

  hipLaunchKernelGGL(k_chan, dim3(co), dim3(1024), 0, stream, m, nib, lutg);
  hipLaunchKernelGGL(k_pmap, dim3(pmb), dim3(256), 0, stream, m, nib, lutg, pmaps, ppart);
  hipLaunchKernelGGL(k_resize, dim3(NT * 225), dim3(256), 0, stream, m, pmaps, ppart, mmaps, rpart);
  hipLaunchKernelGGL(k_fuse, dim3(5 * 225), dim3(256), 0, stream, mmaps, rpart, fusedm, fpart);
  hipLaunchKernelGGL(k_out, dim3(225), dim3(256), 0, stream, fusedm, fpart, (float*)d_out);
}

// Round 10
// 77.248 us; speedup vs baseline: 1.3564x; 1.3564x over previous
//
#include <hip/hip_runtime.h>
#include <math.h>

#define NT 13
#define RHW 57600  // 240*240
#define PIXB 8192  // pixels per chunk for minmax/hist

typedef unsigned long long ull;

struct Meta {
  const float* x[NT];
  int C[NT];
  int H[NT];
  float hsc[NT];            // (float)((double)H/240.0), host-computed
  int pixOff[NT + 1];       // per-tensor pixel offsets
  int nibOff[NT];           // u16 offsets into nibble cache (C*HW/4 per tensor)
  int mmOff[NT + 1];        // (channel,chunk) item offsets
  int nchMM[NT];            // chunks per channel
  int pmOff[NT + 1];        // pmap block offsets (256 px per block)
};

__device__ __forceinline__ int segOf(const int* off, int b) {
  int t = 0;
  while (t + 1 < NT && b >= off[t + 1]) t++;
  return t;
}

// ---------------- K1 body: interior min/max, row-based border logic ----------------
template <int HH>
__device__ __forceinline__ void mm_body(const float* __restrict__ ch, int pix0, int pix1,
                                        float& mn, float& mx) {
  constexpr int W = HH, H = HH;
  int i40 = pix0 >> 2, i41 = pix1 >> 2;
  const float4* __restrict__ P = reinterpret_cast<const float4*>(ch);
  if constexpr (W % 4 == 0) {
    constexpr int W4 = W / 4;
    for (int i4 = i40 + (int)threadIdx.x; i4 < i41; i4 += 256) {
      float4 v = P[i4];
      int h = i4 / W4;           // compile-time magic div
      int c4 = i4 - h * W4;
      if (h > 0 && h < H - 1) {  // interior row: elems 1,2 always interior
        mn = fminf(mn, v.y); mx = fmaxf(mx, v.y);
        mn = fminf(mn, v.z); mx = fmaxf(mx, v.z);
        if (c4 != 0)      { mn = fminf(mn, v.x); mx = fmaxf(mx, v.x); }
        if (c4 != W4 - 1) { mn = fminf(mn, v.w); mx = fmaxf(mx, v.w); }
      }
    }
  } else {  // W==14: generic per-element path
    for (int i4 = i40 + (int)threadIdx.x; i4 < i41; i4 += 256) {
      float4 v = P[i4];
#pragma unroll
      for (int j = 0; j < 4; j++) {
        int idx = i4 * 4 + j;
        int h = idx / W, w = idx - h * W;
        bool ok = h > 0 && h < (H - 1) && w > 0 && w < (W - 1);
        float f = (j == 0) ? v.x : (j == 1) ? v.y : (j == 2) ? v.z : v.w;
        if (ok) { mn = fminf(mn, f); mx = fmaxf(mx, f); }
      }
    }
  }
}

__global__ __launch_bounds__(256) void k_minmax(Meta m, float* cpart) {
  int b = blockIdx.x;
  int t = segOf(m.mmOff, b);
  int local = b - m.mmOff[t];
  int nch = m.nchMM[t];
  int c = local / nch, k = local - c * nch;
  int HW = m.H[t] * m.H[t];
  const float* ch = m.x[t] + (size_t)c * HW;
  int pix0 = k * PIXB, pix1 = min(pix0 + PIXB, HW);
  float mn = INFINITY, mx = -INFINITY;
  switch (m.H[t]) {
    case 224: mm_body<224>(ch, pix0, pix1, mn, mx); break;
    case 112: mm_body<112>(ch, pix0, pix1, mn, mx); break;
    case 56:  mm_body<56>(ch, pix0, pix1, mn, mx); break;
    case 28:  mm_body<28>(ch, pix0, pix1, mn, mx); break;
    default:  mm_body<14>(ch, pix0, pix1, mn, mx); break;
  }
#pragma unroll
  for (int o = 32; o > 0; o >>= 1) {
    mn = fminf(mn, __shfl_down(mn, o));
    mx = fmaxf(mx, __shfl_down(mx, o));
  }
  __shared__ float smn[4], smx[4];
  int wid = threadIdx.x >> 6;
  if ((threadIdx.x & 63) == 0) { smn[wid] = mn; smx[wid] = mx; }
  __syncthreads();
  if (threadIdx.x == 0) {
    for (int i = 1; i < 4; i++) { mn = fminf(mn, smn[i]); mx = fmaxf(mx, smx[i]); }
    cpart[2 * b] = mn; cpart[2 * b + 1] = mx;
  }
}

// ---------------- per-element hist helper: EXACT same arithmetic as R7 ----------------
__device__ __forceinline__ void histElem(float f, float mn, float invd, bool intr, int j,
                                         ull& cbin, ull& clut, unsigned& pack) {
  float vv = (f - mn) * invd * 256.0f;
  float tb = fminf(fmaxf(vv * 0.0234375f, 0.f), 5.f);   // == trunc-then-clamp (v_med3)
  int bin = (int)tb;
  float tl = fminf(fmaxf(vv * 6.0f - 1.0f, 0.f), 5.f);
  int li = (int)tl;
  cbin += (ull)intr << (bin * 10);
  clut += (ull)intr << (li * 10);
  pack |= (unsigned)(intr ? li : 7) << (4 * j);
}

// ---------------- K2 body: hist + nibble, row-based border logic ----------------
template <int HH>
__device__ __forceinline__ void hist_body(const float* __restrict__ ch,
                                          unsigned short* __restrict__ nb,
                                          int pix0, int pix1, float mn, float invd,
                                          ull& cbin, ull& clut) {
  constexpr int W = HH, H = HH;
  int i40 = pix0 >> 2, i41 = pix1 >> 2;
  const float4* __restrict__ P = reinterpret_cast<const float4*>(ch);
  if constexpr (W % 4 == 0) {
    constexpr int W4 = W / 4;
    for (int i4 = i40 + (int)threadIdx.x; i4 < i41; i4 += 256) {
      int h = i4 / W4;
      if (h == 0 || h == H - 1) { nb[i4] = 0x7777u; continue; }  // border row: no load
      float4 v = P[i4];
      int c4 = i4 - h * W4;
      unsigned pack = 0;
      histElem(v.x, mn, invd, c4 != 0, 0, cbin, clut, pack);
      histElem(v.y, mn, invd, true, 1, cbin, clut, pack);
      histElem(v.z, mn, invd, true, 2, cbin, clut, pack);
      histElem(v.w, mn, invd, c4 != W4 - 1, 3, cbin, clut, pack);
      nb[i4] = (unsigned short)pack;
    }
  } else {  // W==14 generic
    for (int i4 = i40 + (int)threadIdx.x; i4 < i41; i4 += 256) {
      float4 v = P[i4];
      unsigned pack = 0;
#pragma unroll
      for (int j = 0; j < 4; j++) {
        int idx = i4 * 4 + j;
        int h = idx / W, w = idx - h * W;
        bool intr = h > 0 && h < (H - 1) && w > 0 && w < (W - 1);
        float f = (j == 0) ? v.x : (j == 1) ? v.y : (j == 2) ? v.z : v.w;
        histElem(f, mn, invd, intr, j, cbin, clut, pack);
      }
      nb[i4] = (unsigned short)pack;
    }
  }
}

__global__ __launch_bounds__(256) void k_histnib(Meta m, const float* __restrict__ cpart,
                                                 unsigned* __restrict__ hpart,
                                                 unsigned short* __restrict__ nib) {
  int b = blockIdx.x;
  int t = segOf(m.mmOff, b);
  int local = b - m.mmOff[t];
  int nch = m.nchMM[t];
  int c = local / nch, k = local - c * nch;
  int H = m.H[t], HW = H * H;
  const float* ch = m.x[t] + (size_t)c * HW;
  // inline reduce of this channel's minmax partials (<=7, chunk-ascending = buildLut order)
  int cb = m.mmOff[t] + c * nch;
  float mn = INFINITY, mx = -INFINITY;
  for (int kk = 0; kk < nch; kk++) {
    mn = fminf(mn, cpart[2 * (cb + kk)]);
    mx = fmaxf(mx, cpart[2 * (cb + kk) + 1]);
  }
  mn = fminf(mn, 0.f);  // fold border zeros
  mx = fmaxf(mx, 0.f);
  float d = mx - mn;
  float invd = d > 0.f ? 1.0f / d : 0.f;
  unsigned short* nb = nib + m.nibOff[t] + (size_t)c * (HW >> 2);
  int pix0 = k * PIXB, pix1 = min(pix0 + PIXB, HW);
  ull cbin = 0ull, clut = 0ull;
  switch (H) {
    case 224: hist_body<224>(ch, nb, pix0, pix1, mn, invd, cbin, clut); break;
    case 112: hist_body<112>(ch, nb, pix0, pix1, mn, invd, cbin, clut); break;
    case 56:  hist_body<56>(ch, nb, pix0, pix1, mn, invd, cbin, clut); break;
    case 28:  hist_body<28>(ch, nb, pix0, pix1, mn, invd, cbin, clut); break;
    default:  hist_body<14>(ch, nb, pix0, pix1, mn, invd, cbin, clut); break;
  }
  // pack lo|hi 16-bit per bin; chunk <= 8192 counts per field -> no carry
  unsigned pk[6];
#pragma unroll
  for (int j = 0; j < 6; j++)
    pk[j] = (unsigned)((cbin >> (10 * j)) & 1023ull) |
            ((unsigned)((clut >> (10 * j)) & 1023ull) << 16);
#pragma unroll
  for (int o = 32; o > 0; o >>= 1) {
#pragma unroll
    for (int j = 0; j < 6; j++) pk[j] += __shfl_down(pk[j], o);
  }
  __shared__ unsigned swh[4][12];
  int wid = threadIdx.x >> 6, lane = threadIdx.x & 63;
  if (lane == 0) {
#pragma unroll
    for (int j = 0; j < 6; j++) { swh[wid][j] = pk[j] & 0xffffu; swh[wid][6 + j] = pk[j] >> 16; }
  }
  __syncthreads();
  if (threadIdx.x < 12)
    hpart[12 * b + threadIdx.x] =
        swh[0][threadIdx.x] + swh[1][threadIdx.x] + swh[2][threadIdx.x] + swh[3][threadIdx.x];
}

// ---------------- per-channel LUT from partials (slots 0-5 interior, 6/7 border) ----------------
__device__ __forceinline__ void buildLut(int c, int H, int HW, int cb, int nch,
                                         const float* __restrict__ cpart,
                                         const unsigned* __restrict__ hpart, float* sLut) {
  float mn = INFINITY, mx = -INFINITY;
  unsigned hh[12];
#pragma unroll
  for (int j = 0; j < 12; j++) hh[j] = 0u;
  for (int k = 0; k < nch; k++) {
    mn = fminf(mn, cpart[2 * (cb + k)]);
    mx = fmaxf(mx, cpart[2 * (cb + k) + 1]);
#pragma unroll
    for (int j = 0; j < 12; j++) hh[j] += hpart[12 * (cb + k) + j];
  }
  mn = fminf(mn, 0.f); mx = fmaxf(mx, 0.f);   // fold border zeros
  float d = mx - mn;
  float invd = d > 0.f ? 1.0f / d : 0.f;
  float fHW = (float)HW;
  int nbp = 4 * H - 4;  // border pixel count (W==H)
  float vb = (0.f - mn) * invd * 256.0f;
  int bin_b = (int)(vb * 0.0234375f);
  bin_b = bin_b < 0 ? 0 : (bin_b > 5 ? 5 : bin_b);
  float ttb = vb * 6.0f - 1.0f;
  int lib = (int)ttb;
  lib = lib < 0 ? 0 : (lib > 5 ? 5 : lib);
  hh[bin_b] += (unsigned)nbp;   // reconstruct full-mask histograms
  hh[6 + lib] += (unsigned)nbp;
  float hl[6];
#pragma unroll
  for (int j = 0; j < 6; j++) hl[j] = -logf((float)hh[j] / fHW + 1e-4f);
  float mn2 = INFINITY, mx2 = -INFINITY, sum2 = 0.f;
#pragma unroll
  for (int j = 0; j < 6; j++) {
    unsigned cc = hh[6 + j];
    if (cc) { mn2 = fminf(mn2, hl[j]); mx2 = fmaxf(mx2, hl[j]); sum2 += (float)cc * hl[j]; }
  }
  float d2 = mx2 - mn2;
  float RL[6];
  if (d2 > 0.f) {
    float meanN = (sum2 / fHW - mn2) / d2;
    float w = 1.0f - meanN; w *= w;
#pragma unroll
    for (int j = 0; j < 6; j++) RL[j] = (hl[j] - mn2) / d2 * w;
  } else {
#pragma unroll
    for (int j = 0; j < 6; j++) RL[j] = 0.f;
  }
  float LUT[7];
  if (c == 0) {
    float mnr = INFINITY, mxr = -INFINITY, sumr = 0.f;
#pragma unroll
    for (int j = 0; j < 6; j++) {
      unsigned cc = hh[6 + j];
      if (cc) { mnr = fminf(mnr, RL[j]); mxr = fmaxf(mxr, RL[j]); sumr += (float)cc * RL[j]; }
    }
    float dr = mxr - mnr;
    if (dr > 0.f) {
      float meanr = sumr / fHW;
      float wp = mxr - meanr; wp *= wp;
#pragma unroll
      for (int j = 0; j < 6; j++) LUT[j] = (RL[j] - mnr) / dr * wp;
      LUT[6] = LUT[lib];
    } else {
#pragma unroll
      for (int j = 0; j < 7; j++) LUT[j] = 0.f;
    }
  } else {
    float mnr = 0.f, mxr = 0.f, sumr = 0.f;
#pragma unroll
    for (int j = 0; j < 6; j++) {
      int cc = (int)hh[6 + j] - (j == lib ? nbp : 0);
      if (cc > 0) { mnr = fminf(mnr, RL[j]); mxr = fmaxf(mxr, RL[j]); sumr += (float)cc * RL[j]; }
    }
    float dr = mxr - mnr;
    if (dr > 0.f) {
      float meanr = sumr / fHW;
      float wp = mxr - meanr; wp *= wp;
#pragma unroll
      for (int j = 0; j < 6; j++) LUT[j] = (RL[j] - mnr) / dr * wp;
      LUT[6] = (0.f - mnr) / dr * wp;
    } else {
#pragma unroll
      for (int j = 0; j < 7; j++) LUT[j] = 0.f;
    }
  }
#pragma unroll
  for (int j = 0; j < 6; j++) sLut[c * 8 + j] = LUT[j];
  sLut[c * 8 + 6] = LUT[6];
  sLut[c * 8 + 7] = LUT[6];   // slot 7 = border
}

// ---------------- K3: p map from nibble cache (LUTs built in-block) ----------------
__global__ __launch_bounds__(256) void k_pmap(Meta m, const float* __restrict__ cpart,
                                              const unsigned* __restrict__ hpart,
                                              const unsigned short* __restrict__ nib,
                                              float* __restrict__ pmaps, float* __restrict__ ppart) {
  __shared__ float sLut[512 * 8];   // 16 KB
  __shared__ float sAcc[4][256];
  int b = blockIdx.x;
  int t = segOf(m.pmOff, b);
  int blk = b - m.pmOff[t];
  int C = m.C[t], H = m.H[t], HW = H * H, i4n = HW >> 2;
  int nch = m.nchMM[t];
  int tid = threadIdx.x, wid = tid >> 6, lane = tid & 63;
  for (int c = tid; c < C; c += 256)
    buildLut(c, H, HW, m.mmOff[t] + c * nch, nch, cpart, hpart, sLut);
  __syncthreads();
  int i4 = blk * 64 + lane;
  bool act = i4 < i4n;
  float a0 = 0.f, a1 = 0.f, a2 = 0.f, a3 = 0.f;
  if (act) {
    const unsigned short* nb = nib + m.nibOff[t] + i4;
    int cpw = C >> 2;
    int c0 = wid * cpw, c1 = c0 + cpw;
#pragma unroll 4
    for (int c = c0; c < c1; ++c) {
      unsigned n = nb[(size_t)c * i4n];
      a0 += sLut[c * 8 + (int)(n & 7u)];
      a1 += sLut[c * 8 + (int)((n >> 4) & 7u)];
      a2 += sLut[c * 8 + (int)((n >> 8) & 7u)];
      a3 += sLut[c * 8 + (int)((n >> 12) & 7u)];
    }
  }
  *reinterpret_cast<float4*>(&sAcc[wid][lane * 4]) = make_float4(a0, a1, a2, a3);
  __syncthreads();
  if (wid == 0) {
    float bmn = INFINITY, bmx = -INFINITY;
    if (act) {
      float t0 = 0.f, t1 = 0.f, t2 = 0.f, t3 = 0.f;
#pragma unroll
      for (int w = 0; w < 4; w++) {   // ascending w == ascending channel blocks (ref order)
        const float* s = &sAcc[w][lane * 4];
        t0 += s[0]; t1 += s[1]; t2 += s[2]; t3 += s[3];
      }
      *reinterpret_cast<float4*>(pmaps + (size_t)m.pixOff[t] + (size_t)i4 * 4) =
          make_float4(t0, t1, t2, t3);
      bmn = fminf(fminf(t0, t1), fminf(t2, t3));
      bmx = fmaxf(fmaxf(t0, t1), fmaxf(t2, t3));
    }
#pragma unroll
    for (int o = 32; o > 0; o >>= 1) {
      bmn = fminf(bmn, __shfl_down(bmn, o));
      bmx = fmaxf(bmx, __shfl_down(bmx, o));
    }
    if (lane == 0) { ppart[2 * b] = bmn; ppart[2 * b + 1] = bmx; }
  }
}

// ---------------- K4: bilinear resize + norm; per-block (mn,mx,sum) partials ----------------
__global__ __launch_bounds__(256) void k_resize(Meta m, const float* pmaps, const float* ppart,
                                                float* mmaps, float* rpart) {
  __shared__ float sMnT, sInvT;
  int t = blockIdx.x / 225;
  int blk = blockIdx.x % 225;
  int wid = threadIdx.x >> 6, lane = threadIdx.x & 63;
  if (wid == 0) {
    int n = m.pmOff[t + 1] - m.pmOff[t];        // <= 196 partials
    const float* pp = ppart + (size_t)m.pmOff[t] * 2;
    float mn = INFINITY, mx = -INFINITY;
    for (int i = lane; i < n; i += 64) { mn = fminf(mn, pp[2 * i]); mx = fmaxf(mx, pp[2 * i + 1]); }
#pragma unroll
    for (int o = 32; o > 0; o >>= 1) {
      mn = fminf(mn, __shfl_down(mn, o));
      mx = fmaxf(mx, __shfl_down(mx, o));
    }
    if (lane == 0) {
      float d = mx - mn;
      sMnT = mn; sInvT = d > 0.f ? 1.0f / d : 0.f;
    }
  }
  __syncthreads();
  int pix = blk * 256 + threadIdx.x;  // 225*256 == 57600 exactly
  int H = m.H[t], W = m.H[t];
  const float* p = pmaps + m.pixOff[t];
  float mn = sMnT, a = sInvT;
  int oy = pix / 240, ox = pix - oy * 240;
  float hs = m.hsc[t];
  float sy = ((float)oy + 0.5f) * hs - 0.5f;
  float sx = ((float)ox + 0.5f) * hs - 0.5f;
  float fy0 = floorf(sy), fx0 = floorf(sx);
  float fy = sy - fy0, fx = sx - fx0;
  int iy0 = (int)fy0, ix0 = (int)fx0;
  int y0 = iy0 < 0 ? 0 : (iy0 > H - 1 ? H - 1 : iy0);
  int y1 = iy0 + 1 < 0 ? 0 : (iy0 + 1 > H - 1 ? H - 1 : iy0 + 1);
  int x0 = ix0 < 0 ? 0 : (ix0 > W - 1 ? W - 1 : ix0);
  int x1 = ix0 + 1 < 0 ? 0 : (ix0 + 1 > W - 1 ? W - 1 : ix0 + 1);
  float v00 = p[y0 * W + x0], v01 = p[y0 * W + x1];
  float v10 = p[y1 * W + x0], v11 = p[y1 * W + x1];
  float r = (1.f - fy) * ((1.f - fx) * v00 + fx * v01) + fy * ((1.f - fx) * v10 + fx * v11);
  float mv = (r - mn) * a;
  mmaps[(size_t)t * RHW + pix] = mv;
  float bmn = mv, bmx = mv, bsm = mv;
#pragma unroll
  for (int o = 32; o > 0; o >>= 1) {
    bmn = fminf(bmn, __shfl_down(bmn, o));
    bmx = fmaxf(bmx, __shfl_down(bmx, o));
    bsm += __shfl_down(bsm, o);
  }
  __shared__ float smn[4], smx[4], ssm[4];
  if ((threadIdx.x & 63) == 0) { smn[wid] = bmn; smx[wid] = bmx; ssm[wid] = bsm; }
  __syncthreads();
  if (threadIdx.x == 0) {
    for (int i = 1; i < 4; i++) { bmn = fminf(bmn, smn[i]); bmx = fmaxf(bmx, smx[i]); bsm += ssm[i]; }
    float* rp = rpart + ((size_t)t * 225 + blk) * 3;
    rp[0] = bmn; rp[1] = bmx; rp[2] = bsm;
  }
}

// ---------------- K5: fuse group (inline partial reduce) ----------------
__global__ __launch_bounds__(256) void k_fuse(const float* mmaps, const float* rpart,
                                              float* fusedm, float* fpart) {
  __shared__ float sMn[3], sD[3], sW[3];
  int g = blockIdx.x / 225;
  int blk = blockIdx.x % 225;
  const int gs[6] = {0, 2, 4, 7, 10, 13};
  int nt = gs[g + 1] - gs[g];
  int wid = threadIdx.x >> 6, lane = threadIdx.x & 63;
  if (wid < nt) {
    int t = gs[g] + wid;
    const float* rp = rpart + (size_t)t * 225 * 3;
    float mn = INFINITY, mx = -INFINITY, sm = 0.f;
    for (int i = lane; i < 225; i += 64) {
      mn = fminf(mn, rp[3 * i]); mx = fmaxf(mx, rp[3 * i + 1]); sm += rp[3 * i + 2];
    }
#pragma unroll
    for (int o = 32; o > 0; o >>= 1) {
      mn = fminf(mn, __shfl_down(mn, o));
      mx = fmaxf(mx, __shfl_down(mx, o));
      sm += __shfl_down(sm, o);
    }
    if (lane == 0) {
      float d = mx - mn;
      if (d > 0.f) {
        float mean = sm * (1.0f / 57600.0f);
        float w = mx - mean; w *= w;
        sMn[wid] = mn; sD[wid] = d; sW[wid] = w;
      } else {
        sMn[wid] = 0.f; sD[wid] = 0.f; sW[wid] = 0.f;
      }
    }
  }
  __syncthreads();
  int pix = blk * 256 + threadIdx.x;
  float acc = 0.f;
  for (int k = 0; k < nt; k++) {
    int t = gs[g] + k;
    if (sD[k] > 0.f) acc += (mmaps[(size_t)t * RHW + pix] - sMn[k]) / sD[k] * sW[k];
  }
  fusedm[(size_t)g * RHW + pix] = acc;
  float bmn = acc, bmx = acc;
#pragma unroll
  for (int o = 32; o > 0; o >>= 1) {
    bmn = fminf(bmn, __shfl_down(bmn, o));
    bmx = fmaxf(bmx, __shfl_down(bmx, o));
  }
  __shared__ float smn[4], smx[4];
  if ((threadIdx.x & 63) == 0) { smn[wid] = bmn; smx[wid] = bmx; }
  __syncthreads();
  if (threadIdx.x == 0) {
    for (int i = 1; i < 4; i++) { bmn = fminf(bmn, smn[i]); bmx = fmaxf(bmx, smx[i]); }
    float* fp = fpart + ((size_t)g * 225 + blk) * 2;
    fp[0] = bmn; fp[1] = bmx;
  }
}

// ---------------- K6: final outputs (inline fstats reduce) ----------------
__global__ __launch_bounds__(256) void k_out(const float* fusedm, const float* fpart, float* out) {
  __shared__ float fmn[5], finv[5];
  int wid = threadIdx.x >> 6, lane = threadIdx.x & 63;
  for (int g = wid; g < 5; g += 4) {
    const float* fp = fpart + (size_t)g * 225 * 2;
    float mn = INFINITY, mx = -INFINITY;
    for (int i = lane; i < 225; i += 64) {
      mn = fminf(mn, fp[2 * i]); mx = fmaxf(mx, fp[2 * i + 1]);
    }
#pragma unroll
    for (int o = 32; o > 0; o >>= 1) {
      mn = fminf(mn, __shfl_down(mn, o));
      mx = fmaxf(mx, __shfl_down(mx, o));
    }
    if (lane == 0) {
      float d = mx - mn;
      fmn[g] = mn; finv[g] = d > 0.f ? 256.0f / d : 0.f;
    }
  }
  __syncthreads();
  int pix = blockIdx.x * 256 + threadIdx.x;
  float acc = 0.f;
  float* out2 = out + RHW;
#pragma unroll
  for (int g = 0; g < 5; g++) {
    float v = (fusedm[(size_t)g * RHW + pix] - fmn[g]) * finv[g];
    out2[(size_t)pix * 5 + g] = v;
    acc += v;
  }
  out[pix] = acc;
}

extern "C" void kernel_launch(void* const* d_in, const int* in_sizes, int n_in,
                              void* d_out, int out_size, void* d_ws, size_t ws_size,
                              hipStream_t stream) {
  static const int Cs[NT] = {64, 64, 128, 128, 256, 256, 256, 512, 512, 512, 512, 512, 512};
  static const int Hs[NT] = {224, 224, 112, 112, 56, 56, 56, 28, 28, 28, 14, 14, 14};
  Meta m;
  int po = 0, mmb = 0, pmb = 0, nibTot = 0;
  for (int t = 0; t < NT; t++) {
    m.x[t] = (const float*)d_in[t];
    m.C[t] = Cs[t]; m.H[t] = Hs[t];
    m.hsc[t] = (float)((double)Hs[t] / 240.0);
    int HW = Hs[t] * Hs[t];
    m.pixOff[t] = po; po += HW;
    m.nibOff[t] = nibTot; nibTot += Cs[t] * (HW >> 2);
    m.mmOff[t] = mmb;
    m.nchMM[t] = (HW + PIXB - 1) / PIXB;
    mmb += Cs[t] * m.nchMM[t];
    m.pmOff[t] = pmb; pmb += (HW + 255) / 256;
  }
  m.pixOff[NT] = po; m.mmOff[NT] = mmb; m.pmOff[NT] = pmb;

  size_t off = 0;
  auto a16 = [](size_t x) { return (x + 15) & ~(size_t)15; };
#define WALLOC(var, type, count) type* var = (type*)((char*)d_ws + off); off = a16(off + sizeof(type) * (size_t)(count));
  WALLOC(cpart, float, 2 * mmb)
  WALLOC(hpart, unsigned, 12 * mmb)
  WALLOC(nib, unsigned short, nibTot)
  WALLOC(ppart, float, 2 * pmb)
  WALLOC(rpart, float, NT * 225 * 3)
  WALLOC(fpart, float, 5 * 225 * 2)
  WALLOC(pmaps, float, po)
  WALLOC(mmaps, float, NT * RHW)
  WALLOC(fusedm, float, 5 * RHW)
#undef WALLOC

  hipLaunchKernelGGL(k_minmax, dim3(mmb), dim3(256), 0, stream, m, cpart);
  hipLaunchKernelGGL(k_histnib, dim3(mmb), dim3(256), 0, stream, m, cpart, hpart, nib);
  hipLaunchKernelGGL(k_pmap, dim3(pmb), dim3(256), 0, stream, m, cpart, hpart, nib, pmaps, ppart);
  hipLaunchKernelGGL(k_resize, dim3(NT * 225), dim3(256), 0, stream, m, pmaps, ppart, mmaps, rpart);
  hipLaunchKernelGGL(k_fuse, dim3(5 * 225), dim3(256), 0, stream, mmaps, rpart, fusedm, fpart);
  hipLaunchKernelGGL(k_out, dim3(225), dim3(256), 0, stream, fusedm, fpart, (float*)d_out);
}

// Round 11
// 76.087 us; speedup vs baseline: 1.3771x; 1.0153x over previous
//
#include <hip/hip_runtime.h>
#include <math.h>

#define NT 13
#define RHW 57600   // 240*240
#define PIXB 12544  // 224^2 = 4 row-aligned chunks; every other channel = 1 chunk

typedef unsigned long long ull;

struct Meta {
  const float* x[NT];
  int C[NT];
  int H[NT];
  float hsc[NT];            // (float)((double)H/240.0), host-computed
  int pixOff[NT + 1];       // per-tensor pixel offsets
  int nibOff[NT];           // u16 offsets into nibble cache (C*HW/4 per tensor)
  int mmOff[NT + 1];        // (channel,chunk) item offsets
  int nchMM[NT];            // chunks per channel (4 for 224^2, else 1)
  int pmOff[NT + 1];        // pmap block offsets (256 px per block)
};

__device__ __forceinline__ int segOf(const int* off, int b) {
  int t = 0;
  while (t + 1 < NT && b >= off[t + 1]) t++;
  return t;
}

// ---------------- interior min/max body, row-based border logic ----------------
template <int HH>
__device__ __forceinline__ void mm_body(const float* __restrict__ ch, int pix0, int pix1,
                                        float& mn, float& mx) {
  constexpr int W = HH, H = HH;
  int i40 = pix0 >> 2, i41 = pix1 >> 2;
  const float4* __restrict__ P = reinterpret_cast<const float4*>(ch);
  if constexpr (W % 4 == 0) {
    constexpr int W4 = W / 4;
    for (int i4 = i40 + (int)threadIdx.x; i4 < i41; i4 += 256) {
      float4 v = P[i4];
      int h = i4 / W4;           // compile-time magic div
      int c4 = i4 - h * W4;
      if (h > 0 && h < H - 1) {  // interior row: elems 1,2 always interior
        mn = fminf(mn, v.y); mx = fmaxf(mx, v.y);
        mn = fminf(mn, v.z); mx = fmaxf(mx, v.z);
        if (c4 != 0)      { mn = fminf(mn, v.x); mx = fmaxf(mx, v.x); }
        if (c4 != W4 - 1) { mn = fminf(mn, v.w); mx = fmaxf(mx, v.w); }
      }
    }
  } else {  // W==14: generic per-element path
    for (int i4 = i40 + (int)threadIdx.x; i4 < i41; i4 += 256) {
      float4 v = P[i4];
#pragma unroll
      for (int j = 0; j < 4; j++) {
        int idx = i4 * 4 + j;
        int h = idx / W, w = idx - h * W;
        bool ok = h > 0 && h < (H - 1) && w > 0 && w < (W - 1);
        float f = (j == 0) ? v.x : (j == 1) ? v.y : (j == 2) ? v.z : v.w;
        if (ok) { mn = fminf(mn, f); mx = fmaxf(mx, f); }
      }
    }
  }
}

// ---------------- per-element hist helper (clamped-truncate == trunc-then-clamp) ----------------
__device__ __forceinline__ void histElem(float f, float mn, float invd, bool intr, int j,
                                         ull& cbin, ull& clut, unsigned& pack) {
  float vv = (f - mn) * invd * 256.0f;
  float tb = fminf(fmaxf(vv * 0.0234375f, 0.f), 5.f);   // v_med3
  int bin = (int)tb;
  float tl = fminf(fmaxf(vv * 6.0f - 1.0f, 0.f), 5.f);
  int li = (int)tl;
  cbin += (ull)intr << (bin * 10);
  clut += (ull)intr << (li * 10);
  pack |= (unsigned)(intr ? li : 7) << (4 * j);
}

// ---------------- hist + nibble body, row-based border logic ----------------
template <int HH>
__device__ __forceinline__ void hist_body(const float* __restrict__ ch,
                                          unsigned short* __restrict__ nb,
                                          int pix0, int pix1, float mn, float invd,
                                          ull& cbin, ull& clut) {
  constexpr int W = HH, H = HH;
  int i40 = pix0 >> 2, i41 = pix1 >> 2;
  const float4* __restrict__ P = reinterpret_cast<const float4*>(ch);
  if constexpr (W % 4 == 0) {
    constexpr int W4 = W / 4;
    for (int i4 = i40 + (int)threadIdx.x; i4 < i41; i4 += 256) {
      int h = i4 / W4;
      if (h == 0 || h == H - 1) { nb[i4] = 0x7777u; continue; }  // border row: no load
      float4 v = P[i4];
      int c4 = i4 - h * W4;
      unsigned pack = 0;
      histElem(v.x, mn, invd, c4 != 0, 0, cbin, clut, pack);
      histElem(v.y, mn, invd, true, 1, cbin, clut, pack);
      histElem(v.z, mn, invd, true, 2, cbin, clut, pack);
      histElem(v.w, mn, invd, c4 != W4 - 1, 3, cbin, clut, pack);
      nb[i4] = (unsigned short)pack;
    }
  } else {  // W==14 generic
    for (int i4 = i40 + (int)threadIdx.x; i4 < i41; i4 += 256) {
      float4 v = P[i4];
      unsigned pack = 0;
#pragma unroll
      for (int j = 0; j < 4; j++) {
        int idx = i4 * 4 + j;
        int h = idx / W, w = idx - h * W;
        bool intr = h > 0 && h < (H - 1) && w > 0 && w < (W - 1);
        float f = (j == 0) ? v.x : (j == 1) ? v.y : (j == 2) ? v.z : v.w;
        histElem(f, mn, invd, intr, j, cbin, clut, pack);
      }
      nb[i4] = (unsigned short)pack;
    }
  }
}

// ---------------- K1: big chunks = minmax partial; small channels = fused minmax+hist+nib ----------------
__global__ __launch_bounds__(256) void k_front(Meta m, float* __restrict__ cpart,
                                               unsigned* __restrict__ hpart,
                                               unsigned short* __restrict__ nib) {
  __shared__ float smn[4], smx[4];
  __shared__ float sMnS, sInvS;
  __shared__ unsigned swh[4][12];
  int b = blockIdx.x;
  int t = segOf(m.mmOff, b);
  int local = b - m.mmOff[t];
  int nch = m.nchMM[t];
  int c = local / nch, k = local - c * nch;
  int H = m.H[t], HW = H * H;
  const float* ch = m.x[t] + (size_t)c * HW;
  int tid = threadIdx.x, wid = tid >> 6, lane = tid & 63;
  int pix0 = k * PIXB, pix1 = min(pix0 + PIXB, HW);

  // pass A: interior min/max over this chunk (== whole channel when nch==1)
  float mn = INFINITY, mx = -INFINITY;
  switch (H) {
    case 224: mm_body<224>(ch, pix0, pix1, mn, mx); break;
    case 112: mm_body<112>(ch, pix0, pix1, mn, mx); break;
    case 56:  mm_body<56>(ch, pix0, pix1, mn, mx); break;
    case 28:  mm_body<28>(ch, pix0, pix1, mn, mx); break;
    default:  mm_body<14>(ch, pix0, pix1, mn, mx); break;
  }
#pragma unroll
  for (int o = 32; o > 0; o >>= 1) {
    mn = fminf(mn, __shfl_down(mn, o));
    mx = fmaxf(mx, __shfl_down(mx, o));
  }
  if (lane == 0) { smn[wid] = mn; smx[wid] = mx; }
  __syncthreads();
  if (tid == 0) {
    for (int i = 1; i < 4; i++) { mn = fminf(mn, smn[i]); mx = fmaxf(mx, smx[i]); }
    cpart[2 * b] = mn; cpart[2 * b + 1] = mx;
    if (nch == 1) {
      float mnf = fminf(mn, 0.f), mxf = fmaxf(mx, 0.f);  // fold border zeros
      float d = mxf - mnf;
      sMnS = mnf; sInvS = d > 0.f ? 1.0f / d : 0.f;
    }
  }
  if (nch > 1) return;   // big 224^2 chunk: minmax partial only (uniform exit)
  __syncthreads();
  float mnc = sMnS, invd = sInvS;

  // pass B (small channels only): hist + nibble, L2-hot re-read of own channel
  unsigned short* nb = nib + m.nibOff[t] + (size_t)c * (HW >> 2);
  ull cbin = 0ull, clut = 0ull;
  switch (H) {
    case 112: hist_body<112>(ch, nb, 0, HW, mnc, invd, cbin, clut); break;
    case 56:  hist_body<56>(ch, nb, 0, HW, mnc, invd, cbin, clut); break;
    case 28:  hist_body<28>(ch, nb, 0, HW, mnc, invd, cbin, clut); break;
    default:  hist_body<14>(ch, nb, 0, HW, mnc, invd, cbin, clut); break;
  }
  // per-lane counts <= 196/field; pack lo|hi 16-bit (block sums <= 12544) and reduce
  unsigned pk[6];
#pragma unroll
  for (int j = 0; j < 6; j++)
    pk[j] = (unsigned)((cbin >> (10 * j)) & 1023ull) |
            ((unsigned)((clut >> (10 * j)) & 1023ull) << 16);
#pragma unroll
  for (int o = 32; o > 0; o >>= 1) {
#pragma unroll
    for (int j = 0; j < 6; j++) pk[j] += __shfl_down(pk[j], o);
  }
  if (lane == 0) {
#pragma unroll
    for (int j = 0; j < 6; j++) { swh[wid][j] = pk[j] & 0xffffu; swh[wid][6 + j] = pk[j] >> 16; }
  }
  __syncthreads();
  if (tid < 12)
    hpart[12 * b + tid] = swh[0][tid] + swh[1][tid] + swh[2][tid] + swh[3][tid];
}

// ---------------- K2: hist + nibble for the 224^2 tensors only (512 chunk blocks) ----------------
__global__ __launch_bounds__(256) void k_histbig(Meta m, const float* __restrict__ cpart,
                                                 unsigned* __restrict__ hpart,
                                                 unsigned short* __restrict__ nib) {
  int b = blockIdx.x;                 // entries 0..511 are tensors 0,1 (nch=4)
  int t = segOf(m.mmOff, b);
  int local = b - m.mmOff[t];
  int nch = m.nchMM[t];
  int c = local / nch, k = local - c * nch;
  int H = m.H[t], HW = H * H;
  const float* ch = m.x[t] + (size_t)c * HW;
  // inline reduce of this channel's minmax partials (chunk-ascending = buildLut order)
  int cb = m.mmOff[t] + c * nch;
  float mn = INFINITY, mx = -INFINITY;
  for (int kk = 0; kk < nch; kk++) {
    mn = fminf(mn, cpart[2 * (cb + kk)]);
    mx = fmaxf(mx, cpart[2 * (cb + kk) + 1]);
  }
  mn = fminf(mn, 0.f);  // fold border zeros
  mx = fmaxf(mx, 0.f);
  float d = mx - mn;
  float invd = d > 0.f ? 1.0f / d : 0.f;
  unsigned short* nb = nib + m.nibOff[t] + (size_t)c * (HW >> 2);
  int pix0 = k * PIXB, pix1 = min(pix0 + PIXB, HW);
  ull cbin = 0ull, clut = 0ull;
  hist_body<224>(ch, nb, pix0, pix1, mn, invd, cbin, clut);
  unsigned pk[6];
#pragma unroll
  for (int j = 0; j < 6; j++)
    pk[j] = (unsigned)((cbin >> (10 * j)) & 1023ull) |
            ((unsigned)((clut >> (10 * j)) & 1023ull) << 16);
#pragma unroll
  for (int o = 32; o > 0; o >>= 1) {
#pragma unroll
    for (int j = 0; j < 6; j++) pk[j] += __shfl_down(pk[j], o);
  }
  __shared__ unsigned swh[4][12];
  int wid = threadIdx.x >> 6, lane = threadIdx.x & 63;
  if (lane == 0) {
#pragma unroll
    for (int j = 0; j < 6; j++) { swh[wid][j] = pk[j] & 0xffffu; swh[wid][6 + j] = pk[j] >> 16; }
  }
  __syncthreads();
  if (threadIdx.x < 12)
    hpart[12 * b + threadIdx.x] =
        swh[0][threadIdx.x] + swh[1][threadIdx.x] + swh[2][threadIdx.x] + swh[3][threadIdx.x];
}

// ---------------- per-channel LUT from partials (slots 0-5 interior, 6/7 border) ----------------
__device__ __forceinline__ void buildLut(int c, int H, int HW, int cb, int nch,
                                         const float* __restrict__ cpart,
                                         const unsigned* __restrict__ hpart, float* sLut) {
  float mn = INFINITY, mx = -INFINITY;
  unsigned hh[12];
#pragma unroll
  for (int j = 0; j < 12; j++) hh[j] = 0u;
  for (int k = 0; k < nch; k++) {
    mn = fminf(mn, cpart[2 * (cb + k)]);
    mx = fmaxf(mx, cpart[2 * (cb + k) + 1]);
#pragma unroll
    for (int j = 0; j < 12; j++) hh[j] += hpart[12 * (cb + k) + j];
  }
  mn = fminf(mn, 0.f); mx = fmaxf(mx, 0.f);   // fold border zeros
  float d = mx - mn;
  float invd = d > 0.f ? 1.0f / d : 0.f;
  float fHW = (float)HW;
  int nbp = 4 * H - 4;  // border pixel count (W==H)
  float vb = (0.f - mn) * invd * 256.0f;
  int bin_b = (int)(vb * 0.0234375f);
  bin_b = bin_b < 0 ? 0 : (bin_b > 5 ? 5 : bin_b);
  float ttb = vb * 6.0f - 1.0f;
  int lib = (int)ttb;
  lib = lib < 0 ? 0 : (lib > 5 ? 5 : lib);
  hh[bin_b] += (unsigned)nbp;   // reconstruct full-mask histograms
  hh[6 + lib] += (unsigned)nbp;
  float hl[6];
#pragma unroll
  for (int j = 0; j < 6; j++) hl[j] = -logf((float)hh[j] / fHW + 1e-4f);
  float mn2 = INFINITY, mx2 = -INFINITY, sum2 = 0.f;
#pragma unroll
  for (int j = 0; j < 6; j++) {
    unsigned cc = hh[6 + j];
    if (cc) { mn2 = fminf(mn2, hl[j]); mx2 = fmaxf(mx2, hl[j]); sum2 += (float)cc * hl[j]; }
  }
  float d2 = mx2 - mn2;
  float RL[6];
  if (d2 > 0.f) {
    float meanN = (sum2 / fHW - mn2) / d2;
    float w = 1.0f - meanN; w *= w;
#pragma unroll
    for (int j = 0; j < 6; j++) RL[j] = (hl[j] - mn2) / d2 * w;
  } else {
#pragma unroll
    for (int j = 0; j < 6; j++) RL[j] = 0.f;
  }
  float LUT[7];
  if (c == 0) {
    float mnr = INFINITY, mxr = -INFINITY, sumr = 0.f;
#pragma unroll
    for (int j = 0; j < 6; j++) {
      unsigned cc = hh[6 + j];
      if (cc) { mnr = fminf(mnr, RL[j]); mxr = fmaxf(mxr, RL[j]); sumr += (float)cc * RL[j]; }
    }
    float dr = mxr - mnr;
    if (dr > 0.f) {
      float meanr = sumr / fHW;
      float wp = mxr - meanr; wp *= wp;
#pragma unroll
      for (int j = 0; j < 6; j++) LUT[j] = (RL[j] - mnr) / dr * wp;
      LUT[6] = LUT[lib];
    } else {
#pragma unroll
      for (int j = 0; j < 7; j++) LUT[j] = 0.f;
    }
  } else {
    float mnr = 0.f, mxr = 0.f, sumr = 0.f;
#pragma unroll
    for (int j = 0; j < 6; j++) {
      int cc = (int)hh[6 + j] - (j == lib ? nbp : 0);
      if (cc > 0) { mnr = fminf(mnr, RL[j]); mxr = fmaxf(mxr, RL[j]); sumr += (float)cc * RL[j]; }
    }
    float dr = mxr - mnr;
    if (dr > 0.f) {
      float meanr = sumr / fHW;
      float wp = mxr - meanr; wp *= wp;
#pragma unroll
      for (int j = 0; j < 6; j++) LUT[j] = (RL[j] - mnr) / dr * wp;
      LUT[6] = (0.f - mnr) / dr * wp;
    } else {
#pragma unroll
      for (int j = 0; j < 7; j++) LUT[j] = 0.f;
    }
  }
#pragma unroll
  for (int j = 0; j < 6; j++) sLut[c * 8 + j] = LUT[j];
  sLut[c * 8 + 6] = LUT[6];
  sLut[c * 8 + 7] = LUT[6];   // slot 7 = border
}

// ---------------- K3: p map from nibble cache (LUTs built in-block) ----------------
__global__ __launch_bounds__(256) void k_pmap(Meta m, const float* __restrict__ cpart,
                                              const unsigned* __restrict__ hpart,
                                              const unsigned short* __restrict__ nib,
                                              float* __restrict__ pmaps, float* __restrict__ ppart) {
  __shared__ float sLut[512 * 8];   // 16 KB
  __shared__ float sAcc[4][256];
  int b = blockIdx.x;
  int t = segOf(m.pmOff, b);
  int blk = b - m.pmOff[t];
  int C = m.C[t], H = m.H[t], HW = H * H, i4n = HW >> 2;
  int nch = m.nchMM[t];
  int tid = threadIdx.x, wid = tid >> 6, lane = tid & 63;
  for (int c = tid; c < C; c += 256)
    buildLut(c, H, HW, m.mmOff[t] + c * nch, nch, cpart, hpart, sLut);
  __syncthreads();
  int i4 = blk * 64 + lane;
  bool act = i4 < i4n;
  float a0 = 0.f, a1 = 0.f, a2 = 0.f, a3 = 0.f;
  if (act) {
    const unsigned short* nb = nib + m.nibOff[t] + i4;
    int cpw = C >> 2;
    int c0 = wid * cpw, c1 = c0 + cpw;
#pragma unroll 4
    for (int c = c0; c < c1; ++c) {
      unsigned n = nb[(size_t)c * i4n];
      a0 += sLut[c * 8 + (int)(n & 7u)];
      a1 += sLut[c * 8 + (int)((n >> 4) & 7u)];
      a2 += sLut[c * 8 + (int)((n >> 8) & 7u)];
      a3 += sLut[c * 8 + (int)((n >> 12) & 7u)];
    }
  }
  *reinterpret_cast<float4*>(&sAcc[wid][lane * 4]) = make_float4(a0, a1, a2, a3);
  __syncthreads();
  if (wid == 0) {
    float bmn = INFINITY, bmx = -INFINITY;
    if (act) {
      float t0 = 0.f, t1 = 0.f, t2 = 0.f, t3 = 0.f;
#pragma unroll
      for (int w = 0; w < 4; w++) {   // ascending w == ascending channel blocks (ref order)
        const float* s = &sAcc[w][lane * 4];
        t0 += s[0]; t1 += s[1]; t2 += s[2]; t3 += s[3];
      }
      *reinterpret_cast<float4*>(pmaps + (size_t)m.pixOff[t] + (size_t)i4 * 4) =
          make_float4(t0, t1, t2, t3);
      bmn = fminf(fminf(t0, t1), fminf(t2, t3));
      bmx = fmaxf(fmaxf(t0, t1), fmaxf(t2, t3));
    }
#pragma unroll
    for (int o = 32; o > 0; o >>= 1) {
      bmn = fminf(bmn, __shfl_down(bmn, o));
      bmx = fmaxf(bmx, __shfl_down(bmx, o));
    }
    if (lane == 0) { ppart[2 * b] = bmn; ppart[2 * b + 1] = bmx; }
  }
}

// ---------------- K4: bilinear resize + norm; per-block (mn,mx,sum) partials ----------------
__global__ __launch_bounds__(256) void k_resize(Meta m, const float* pmaps, const float* ppart,
                                                float* mmaps, float* rpart) {
  __shared__ float sMnT, sInvT;
  int t = blockIdx.x / 225;
  int blk = blockIdx.x % 225;
  int wid = threadIdx.x >> 6, lane = threadIdx.x & 63;
  if (wid == 0) {
    int n = m.pmOff[t + 1] - m.pmOff[t];        // <= 196 partials
    const float* pp = ppart + (size_t)m.pmOff[t] * 2;
    float mn = INFINITY, mx = -INFINITY;
    for (int i = lane; i < n; i += 64) { mn = fminf(mn, pp[2 * i]); mx = fmaxf(mx, pp[2 * i + 1]); }
#pragma unroll
    for (int o = 32; o > 0; o >>= 1) {
      mn = fminf(mn, __shfl_down(mn, o));
      mx = fmaxf(mx, __shfl_down(mx, o));
    }
    if (lane == 0) {
      float d = mx - mn;
      sMnT = mn; sInvT = d > 0.f ? 1.0f / d : 0.f;
    }
  }
  __syncthreads();
  int pix = blk * 256 + threadIdx.x;  // 225*256 == 57600 exactly
  int H = m.H[t], W = m.H[t];
  const float* p = pmaps + m.pixOff[t];
  float mn = sMnT, a = sInvT;
  int oy = pix / 240, ox = pix - oy * 240;
  float hs = m.hsc[t];
  float sy = ((float)oy + 0.5f) * hs - 0.5f;
  float sx = ((float)ox + 0.5f) * hs - 0.5f;
  float fy0 = floorf(sy), fx0 = floorf(sx);
  float fy = sy - fy0, fx = sx - fx0;
  int iy0 = (int)fy0, ix0 = (int)fx0;
  int y0 = iy0 < 0 ? 0 : (iy0 > H - 1 ? H - 1 : iy0);
  int y1 = iy0 + 1 < 0 ? 0 : (iy0 + 1 > H - 1 ? H - 1 : iy0 + 1);
  int x0 = ix0 < 0 ? 0 : (ix0 > W - 1 ? W - 1 : ix0);
  int x1 = ix0 + 1 < 0 ? 0 : (ix0 + 1 > W - 1 ? W - 1 : ix0 + 1);
  float v00 = p[y0 * W + x0], v01 = p[y0 * W + x1];
  float v10 = p[y1 * W + x0], v11 = p[y1 * W + x1];
  float r = (1.f - fy) * ((1.f - fx) * v00 + fx * v01) + fy * ((1.f - fx) * v10 + fx * v11);
  float mv = (r - mn) * a;
  mmaps[(size_t)t * RHW + pix] = mv;
  float bmn = mv, bmx = mv, bsm = mv;
#pragma unroll
  for (int o = 32; o > 0; o >>= 1) {
    bmn = fminf(bmn, __shfl_down(bmn, o));
    bmx = fmaxf(bmx, __shfl_down(bmx, o));
    bsm += __shfl_down(bsm, o);
  }
  __shared__ float smn[4], smx[4], ssm[4];
  if ((threadIdx.x & 63) == 0) { smn[wid] = bmn; smx[wid] = bmx; ssm[wid] = bsm; }
  __syncthreads();
  if (threadIdx.x == 0) {
    for (int i = 1; i < 4; i++) { bmn = fminf(bmn, smn[i]); bmx = fmaxf(bmx, smx[i]); bsm += ssm[i]; }
    float* rp = rpart + ((size_t)t * 225 + blk) * 3;
    rp[0] = bmn; rp[1] = bmx; rp[2] = bsm;
  }
}

// ---------------- K5: fuse group (inline partial reduce) ----------------
__global__ __launch_bounds__(256) void k_fuse(const float* mmaps, const float* rpart,
                                              float* fusedm, float* fpart) {
  __shared__ float sMn[3], sD[3], sW[3];
  int g = blockIdx.x / 225;
  int blk = blockIdx.x % 225;
  const int gs[6] = {0, 2, 4, 7, 10, 13};
  int nt = gs[g + 1] - gs[g];
  int wid = threadIdx.x >> 6, lane = threadIdx.x & 63;
  if (wid < nt) {
    int t = gs[g] + wid;
    const float* rp = rpart + (size_t)t * 225 * 3;
    float mn = INFINITY, mx = -INFINITY, sm = 0.f;
    for (int i = lane; i < 225; i += 64) {
      mn = fminf(mn, rp[3 * i]); mx = fmaxf(mx, rp[3 * i + 1]); sm += rp[3 * i + 2];
    }
#pragma unroll
    for (int o = 32; o > 0; o >>= 1) {
      mn = fminf(mn, __shfl_down(mn, o));
      mx = fmaxf(mx, __shfl_down(mx, o));
      sm += __shfl_down(sm, o);
    }
    if (lane == 0) {
      float d = mx - mn;
      if (d > 0.f) {
        float mean = sm * (1.0f / 57600.0f);
        float w = mx - mean; w *= w;
        sMn[wid] = mn; sD[wid] = d; sW[wid] = w;
      } else {
        sMn[wid] = 0.f; sD[wid] = 0.f; sW[wid] = 0.f;
      }
    }
  }
  __syncthreads();
  int pix = blk * 256 + threadIdx.x;
  float acc = 0.f;
  for (int k = 0; k < nt; k++) {
    int t = gs[g] + k;
    if (sD[k] > 0.f) acc += (mmaps[(size_t)t * RHW + pix] - sMn[k]) / sD[k] * sW[k];
  }
  fusedm[(size_t)g * RHW + pix] = acc;
  float bmn = acc, bmx = acc;
#pragma unroll
  for (int o = 32; o > 0; o >>= 1) {
    bmn = fminf(bmn, __shfl_down(bmn, o));
    bmx = fmaxf(bmx, __shfl_down(bmx, o));
  }
  __shared__ float smn[4], smx[4];
  if ((threadIdx.x & 63) == 0) { smn[wid] = bmn; smx[wid] = bmx; }
  __syncthreads();
  if (threadIdx.x == 0) {
    for (int i = 1; i < 4; i++) { bmn = fminf(bmn, smn[i]); bmx = fmaxf(bmx, smx[i]); }
    float* fp = fpart + ((size_t)g * 225 + blk) * 2;
    fp[0] = bmn; fp[1] = bmx;
  }
}

// ---------------- K6: final outputs (inline fstats reduce) ----------------
__global__ __launch_bounds__(256) void k_out(const float* fusedm, const float* fpart, float* out) {
  __shared__ float fmn[5], finv[5];
  int wid = threadIdx.x >> 6, lane = threadIdx.x & 63;
  for (int g = wid; g < 5; g += 4) {
    const float* fp = fpart + (size_t)g * 225 * 2;
    float mn = INFINITY, mx = -INFINITY;
    for (int i = lane; i < 225; i += 64) {
      mn = fminf(mn, fp[2 * i]); mx = fmaxf(mx, fp[2 * i + 1]);
    }
#pragma unroll
    for (int o = 32; o > 0; o >>= 1) {
      mn = fminf(mn, __shfl_down(mn, o));
      mx = fmaxf(mx, __shfl_down(mx, o));
    }
    if (lane == 0) {
      float d = mx - mn;
      fmn[g] = mn; finv[g] = d > 0.f ? 256.0f / d : 0.f;
    }
  }
  __syncthreads();
  int pix = blockIdx.x * 256 + threadIdx.x;
  float acc = 0.f;
  float* out2 = out + RHW;
#pragma unroll
  for (int g = 0; g < 5; g++) {
    float v = (fusedm[(size_t)g * RHW + pix] - fmn[g]) * finv[g];
    out2[(size_t)pix * 5 + g] = v;
    acc += v;
  }
  out[pix] = acc;
}

extern "C" void kernel_launch(void* const* d_in, const int* in_sizes, int n_in,
                              void* d_out, int out_size, void* d_ws, size_t ws_size,
                              hipStream_t stream) {
  static const int Cs[NT] = {64, 64, 128, 128, 256, 256, 256, 512, 512, 512, 512, 512, 512};
  static const int Hs[NT] = {224, 224, 112, 112, 56, 56, 56, 28, 28, 28, 14, 14, 14};
  Meta m;
  int po = 0, mmb = 0, pmb = 0, nibTot = 0, bigCnt = 0;
  for (int t = 0; t < NT; t++) {
    m.x[t] = (const float*)d_in[t];
    m.C[t] = Cs[t]; m.H[t] = Hs[t];
    m.hsc[t] = (float)((double)Hs[t] / 240.0);
    int HW = Hs[t] * Hs[t];
    m.pixOff[t] = po; po += HW;
    m.nibOff[t] = nibTot; nibTot += Cs[t] * (HW >> 2);
    m.mmOff[t] = mmb;
    m.nchMM[t] = (HW + PIXB - 1) / PIXB;   // 4 for 224^2, else 1
    mmb += Cs[t] * m.nchMM[t];
    if (m.nchMM[t] > 1) bigCnt += Cs[t] * m.nchMM[t];
    m.pmOff[t] = pmb; pmb += (HW + 255) / 256;
  }
  m.pixOff[NT] = po; m.mmOff[NT] = mmb; m.pmOff[NT] = pmb;

  size_t off = 0;
  auto a16 = [](size_t x) { return (x + 15) & ~(size_t)15; };
#define WALLOC(var, type, count) type* var = (type*)((char*)d_ws + off); off = a16(off + sizeof(type) * (size_t)(count));
  WALLOC(cpart, float, 2 * mmb)
  WALLOC(hpart, unsigned, 12 * mmb)
  WALLOC(nib, unsigned short, nibTot)
  WALLOC(ppart, float, 2 * pmb)
  WALLOC(rpart, float, NT * 225 * 3)
  WALLOC(fpart, float, 5 * 225 * 2)
  WALLOC(pmaps, float, po)
  WALLOC(mmaps, float, NT * RHW)
  WALLOC(fusedm, float, 5 * RHW)
#undef WALLOC

  hipLaunchKernelGGL(k_front, dim3(mmb), dim3(256), 0, stream, m, cpart, hpart, nib);
  hipLaunchKernelGGL(k_histbig, dim3(bigCnt), dim3(256), 0, stream, m, cpart, hpart, nib);
  hipLaunchKernelGGL(k_pmap, dim3(pmb), dim3(256), 0, stream, m, cpart, hpart, nib, pmaps, ppart);
  hipLaunchKernelGGL(k_resize, dim3(NT * 225), dim3(256), 0, stream, m, pmaps, ppart, mmaps, rpart);
  hipLaunchKernelGGL(k_fuse, dim3(5 * 225), dim3(256), 0, stream, mmaps, rpart, fusedm, fpart);
  hipLaunchKernelGGL(k_out, dim3(225), dim3(256), 0, stream, fusedm, fpart, (float*)d_out);
}